// Round 4
// baseline (138.361 us; speedup 1.0000x reference)
//
#include <hip/hip_runtime.h>

// B=16, Q=256, K=256, H=256, DV=256
#define Bn 16
#define Qn 256
#define Kn 256
#define Hn 256
#define DVn 256

constexpr float C2    = 2.8853900817779268f;   // 2/ln2 : e^{2x} = 2^(C2*x)
constexpr float LOG2E = 1.4426950408889634f;

__device__ __forceinline__ float fast_exp2(float x) { return __builtin_amdgcn_exp2f(x); }
__device__ __forceinline__ float fast_rcp(float x)  { return __builtin_amdgcn_rcpf(x); }

__device__ __forceinline__ unsigned short f2bf(float x) {   // RNE fp32->bf16
    unsigned u = __float_as_uint(x);
    u += 0x7fffu + ((u >> 16) & 1u);
    return (unsigned short)(u >> 16);
}

// ------------------------------------------------------------------
// K1: z=0: Eq = exp(2*(queries @ W_q^T))  fp32 row-major [4096][256]
//     z=1: Ek = exp(2*(keys    @ W_k^T))  bf16 interleaved [b][h/4][k][4]
//     z=2: Vp = V re-tiled to k-quads     fp32 [b][k/4][dv][4]
// GEMM: 64x64 tile, BK=16, 256 threads, 4x4 micro-tile, double-buffered.
// grid (4, 64, 3) = 768 blocks.
// ------------------------------------------------------------------
__global__ __launch_bounds__(256)
void proj_exp_kernel(const float* __restrict__ q, const float* __restrict__ kx,
                     const float* __restrict__ wq, const float* __restrict__ wk,
                     const float* __restrict__ V,
                     float* __restrict__ Eq, unsigned short* __restrict__ Ekb,
                     float* __restrict__ Vp)
{
    const int z = blockIdx.z;
    const int tid = threadIdx.x;
    if (z == 2) {
        // V re-tile: quad index p = (b*64 + k4)*256 + dv ; Vp[p*4 + r] = V[(b*256+4*k4+r)*256+dv]
        const int L = blockIdx.y * 4 + blockIdx.x;        // 0..255
        #pragma unroll
        for (int j = 0; j < 4; ++j) {
            const int p   = L * 1024 + j * 256 + tid;
            const int bk4 = p >> 8;                        // b*64 + k4
            const int dv  = p & 255;
            const int b   = bk4 >> 6, k4 = bk4 & 63;
            const float* src = V + ((size_t)(b * Kn + 4 * k4)) * DVn + dv;
            float4 o;
            o.x = src[0 * DVn]; o.y = src[1 * DVn]; o.z = src[2 * DVn]; o.w = src[3 * DVn];
            *(float4*)(Vp + (size_t)p * 4) = o;
        }
        return;
    }
    const float* A = z ? kx : q;
    const float* W = z ? wk : wq;
    const int m0 = blockIdx.y * 64;
    const int n0 = blockIdx.x * 64;
    __shared__ __align__(16) float As[2][16][68];
    __shared__ __align__(16) float Bs[2][16][68];
    const int tx = tid & 15, ty = tid >> 4;
    const int lr = tid >> 2, lk4 = (tid & 3) * 4;
    const float* Arow = A + (size_t)(m0 + lr) * Hn + lk4;
    const float* Wrow = W + (size_t)(n0 + lr) * Hn + lk4;
    {
        float4 a = *(const float4*)(Arow);
        float4 w = *(const float4*)(Wrow);
        As[0][lk4+0][lr] = a.x; As[0][lk4+1][lr] = a.y; As[0][lk4+2][lr] = a.z; As[0][lk4+3][lr] = a.w;
        Bs[0][lk4+0][lr] = w.x; Bs[0][lk4+1][lr] = w.y; Bs[0][lk4+2][lr] = w.z; Bs[0][lk4+3][lr] = w.w;
    }
    __syncthreads();
    float acc[4][4] = {};
    int cur = 0;
    for (int k0 = 0; k0 < Hn; k0 += 16) {
        float4 an, wn;
        const bool more = (k0 + 16 < Hn);
        if (more) {
            an = *(const float4*)(Arow + k0 + 16);
            wn = *(const float4*)(Wrow + k0 + 16);
        }
        #pragma unroll
        for (int kk = 0; kk < 16; ++kk) {
            float4 av = *(const float4*)&As[cur][kk][ty*4];
            float4 bv = *(const float4*)&Bs[cur][kk][tx*4];
            const float ar[4] = {av.x, av.y, av.z, av.w};
            const float br[4] = {bv.x, bv.y, bv.z, bv.w};
            #pragma unroll
            for (int i = 0; i < 4; ++i)
                #pragma unroll
                for (int j = 0; j < 4; ++j)
                    acc[i][j] = fmaf(ar[i], br[j], acc[i][j]);
        }
        if (more) {
            const int nxt = cur ^ 1;
            As[nxt][lk4+0][lr] = an.x; As[nxt][lk4+1][lr] = an.y; As[nxt][lk4+2][lr] = an.z; As[nxt][lk4+3][lr] = an.w;
            Bs[nxt][lk4+0][lr] = wn.x; Bs[nxt][lk4+1][lr] = wn.y; Bs[nxt][lk4+2][lr] = wn.z; Bs[nxt][lk4+3][lr] = wn.w;
            __syncthreads();
            cur = nxt;
        }
    }
    #pragma unroll
    for (int i = 0; i < 4; ++i) {
        float4 o;
        o.x = fast_exp2(C2 * acc[i][0]);
        o.y = fast_exp2(C2 * acc[i][1]);
        o.z = fast_exp2(C2 * acc[i][2]);
        o.w = fast_exp2(C2 * acc[i][3]);
        if (z == 0) {
            *(float4*)(Eq + (size_t)(m0 + ty*4 + i) * Hn + n0 + tx*4) = o;
        } else {
            const int m  = m0 + ty*4 + i;        // = b*256 + k
            const int bq = m >> 8, kk2 = m & 255;
            const int hg = (n0 + tx*4) >> 2;     // h/4
            ushort4 s;
            s.x = f2bf(o.x); s.y = f2bf(o.y); s.z = f2bf(o.z); s.w = f2bf(o.w);
            *(ushort4*)(Ekb + ((size_t)(bq * 64 + hg) * 256 + kk2) * 4) = s;
        }
    }
}

// ------------------------------------------------------------------
// K2 fused: scores + softmax + PV -> out
// grid (Q/8=32, B=16), block 256. Thread t owns k-column t for 8 q-rows.
//   score(q,k) = -2 * sum_h wv[h] * rcp(1 + Eq[q,h]*Ek[k,h])  (softmax shift-inv)
// ek: bf16 packed, 4 coalesced dwordx2 per 16-h chunk, prefetched
// V : fp32 k-quad layout, 1 b128 per 4-k, prefetched
// ------------------------------------------------------------------
__global__ __launch_bounds__(256)
void fused_attn_kernel(const float* __restrict__ Eq, const unsigned short* __restrict__ Ekb,
                       const float* __restrict__ wv, const float* __restrict__ Vp,
                       float* __restrict__ out)
{
    const int b  = blockIdx.y;
    const int q0 = blockIdx.x * 8;
    __shared__ __align__(16) float sEq[8 * 256];
    __shared__ __align__(16) float swv[256];
    __shared__ __align__(16) float sP[8 * 260];
    __shared__ float sredM[8][4];
    __shared__ float sredS[8][4];
    const int tid = threadIdx.x;
    #pragma unroll
    for (int r = 0; r < 2; ++r) {
        const int i = tid + r * 256;
        const int qq = i >> 6, h4 = (i & 63) * 4;
        *(float4*)&sEq[qq*256 + h4] = *(const float4*)(Eq + (size_t)(b*Qn + q0 + qq) * Hn + h4);
    }
    swv[tid] = wv[tid];
    __syncthreads();

    float sc[8] = {};
    // ek uint2 index: b*16384 + hg*256 + t  (hg = h/4)
    const uint2* ekp = (const uint2*)Ekb + (size_t)b * 16384 + tid;
    uint2 e[4];
    #pragma unroll
    for (int g = 0; g < 4; ++g) e[g] = ekp[g * 256];
    for (int it = 0; it < 16; ++it) {
        uint2 en[4];
        if (it < 15) {
            #pragma unroll
            for (int g = 0; g < 4; ++g) en[g] = ekp[(4*(it+1) + g) * 256];
        }
        const int h0 = it * 16;
        float ek[16];
        #pragma unroll
        for (int g = 0; g < 4; ++g) {
            ek[4*g+0] = __uint_as_float(e[g].x << 16);
            ek[4*g+1] = __uint_as_float(e[g].x & 0xFFFF0000u);
            ek[4*g+2] = __uint_as_float(e[g].y << 16);
            ek[4*g+3] = __uint_as_float(e[g].y & 0xFFFF0000u);
        }
        #pragma unroll
        for (int qq = 0; qq < 8; ++qq) {
            float a = sc[qq];
            #pragma unroll
            for (int g = 0; g < 4; ++g) {
                const float4 ea = *(const float4*)&sEq[qq*256 + h0 + 4*g];
                const float4 wa = *(const float4*)&swv[h0 + 4*g];
                a = fmaf(wa.x, fast_rcp(fmaf(ea.x, ek[4*g+0], 1.f)), a);
                a = fmaf(wa.y, fast_rcp(fmaf(ea.y, ek[4*g+1], 1.f)), a);
                a = fmaf(wa.z, fast_rcp(fmaf(ea.z, ek[4*g+2], 1.f)), a);
                a = fmaf(wa.w, fast_rcp(fmaf(ea.w, ek[4*g+3], 1.f)), a);
            }
            sc[qq] = a;
        }
        #pragma unroll
        for (int g = 0; g < 4; ++g) e[g] = en[g];
    }

    // ---- softmax over k (scores = -2*sc) ----
    const int w = tid >> 6, lane = tid & 63;
    #pragma unroll
    for (int qq = 0; qq < 8; ++qq) {
        sc[qq] = -2.0f * sc[qq];
        float mx = sc[qq];
        #pragma unroll
        for (int off = 32; off; off >>= 1) mx = fmaxf(mx, __shfl_xor(mx, off, 64));
        if (lane == 0) sredM[qq][w] = mx;
    }
    __syncthreads();
    #pragma unroll
    for (int qq = 0; qq < 8; ++qq) {
        const float mx = fmaxf(fmaxf(sredM[qq][0], sredM[qq][1]),
                               fmaxf(sredM[qq][2], sredM[qq][3]));
        const float p = fast_exp2(LOG2E * (sc[qq] - mx));
        float s = p;
        #pragma unroll
        for (int off = 32; off; off >>= 1) s += __shfl_xor(s, off, 64);
        if (lane == 0) sredS[qq][w] = s;
        sP[qq*260 + tid] = p;
    }
    __syncthreads();
    float rinv[8];
    #pragma unroll
    for (int qq = 0; qq < 8; ++qq)
        rinv[qq] = fast_rcp(sredS[qq][0] + sredS[qq][1] + sredS[qq][2] + sredS[qq][3]);

    // ---- PV: thread owns dv = tid, 8 q-rows; V in k-quad layout ----
    float acc[8] = {};
    const float4* vp = (const float4*)Vp + (size_t)b * 64 * 256 + tid;  // [k4][dv] quads
    float4 vv = vp[0];
    for (int k4 = 0; k4 < 64; ++k4) {
        float4 vn;
        if (k4 < 63) vn = vp[(k4 + 1) * 256];
        #pragma unroll
        for (int qq = 0; qq < 8; ++qq) {
            const float4 pq = *(const float4*)&sP[qq*260 + 4*k4];
            float a = acc[qq];
            a = fmaf(pq.x, vv.x, a);
            a = fmaf(pq.y, vv.y, a);
            a = fmaf(pq.z, vv.z, a);
            a = fmaf(pq.w, vv.w, a);
            acc[qq] = a;
        }
        vv = vn;
    }
    float* ob = out + (size_t)(b*Qn + q0) * DVn + tid;
    #pragma unroll
    for (int qq = 0; qq < 8; ++qq)
        ob[(size_t)qq * DVn] = acc[qq] * rinv[qq];
}

extern "C" void kernel_launch(void* const* d_in, const int* in_sizes, int n_in,
                              void* d_out, int out_size, void* d_ws, size_t ws_size,
                              hipStream_t stream) {
    const float* queries = (const float*)d_in[0];  // [16,256,256]
    const float* keys    = (const float*)d_in[1];  // [16,256,256]
    const float* values  = (const float*)d_in[2];  // [16,256,256]
    const float* W_q     = (const float*)d_in[3];  // [256,256]
    const float* W_k     = (const float*)d_in[4];  // [256,256]
    const float* w_v     = (const float*)d_in[5];  // [256]
    float* out = (float*)d_out;

    // workspace: Eq fp32 4MB | Ek bf16 2MB | Vp fp32 4MB
    float*          Eq  = (float*)d_ws;
    unsigned short* Ekb = (unsigned short*)(Eq + (size_t)Bn * Qn * Hn);
    float*          Vp  = (float*)(Ekb + (size_t)Bn * Kn * Hn);

    proj_exp_kernel<<<dim3(4, 64, 3), 256, 0, stream>>>(queries, keys, W_q, W_k, values,
                                                        Eq, Ekb, Vp);
    fused_attn_kernel<<<dim3(32, 16), 256, 0, stream>>>(Eq, Ekb, w_v, Vp, out);
}

// Round 5
// 138.226 us; speedup vs baseline: 1.0010x; 1.0010x over previous
//
#include <hip/hip_runtime.h>

// B=16, Q=256, K=256, H=256, DV=256
#define Bn 16
#define Qn 256
#define Kn 256
#define Hn 256
#define DVn 256

constexpr float C2    = 2.8853900817779268f;   // 2/ln2 : e^{2x} = 2^(C2*x)
constexpr float LOG2E = 1.4426950408889634f;

typedef float v2f __attribute__((ext_vector_type(2)));

__device__ __forceinline__ float fast_exp2(float x) { return __builtin_amdgcn_exp2f(x); }
__device__ __forceinline__ float fast_rcp(float x)  { return __builtin_amdgcn_rcpf(x); }
__device__ __forceinline__ v2f pk_fma(v2f a, v2f b, v2f c) {
    return __builtin_elementwise_fma(a, b, c);
}

__device__ __forceinline__ unsigned short f2bf(float x) {   // RNE fp32->bf16
    unsigned u = __float_as_uint(x);
    u += 0x7fffu + ((u >> 16) & 1u);
    return (unsigned short)(u >> 16);
}

// packed reciprocal of x (x >= 1): magic seed + 2 Newton iters, rel err ~1e-5
__device__ __forceinline__ v2f pk_rcp(v2f x) {
    uint2 u = __builtin_bit_cast(uint2, x);
    u.x = 0x7EF311C3u - u.x;
    u.y = 0x7EF311C3u - u.y;
    v2f y = __builtin_bit_cast(v2f, u);
    const v2f two = {2.0f, 2.0f};
    v2f t = pk_fma(-x, y, two);
    y = y * t;
    t = pk_fma(-x, y, two);
    y = y * t;
    return y;
}

// ------------------------------------------------------------------
// K1: z=0: Eq = exp(2*(queries @ W_q^T))  fp32 row-major [4096][256]
//     z=1: Ek = exp(2*(keys    @ W_k^T))  bf16 interleaved [b][h/4][k][4]
//     z=2: Vp = V re-tiled to k-quads     fp32 [b][k/4][dv][4]
// GEMM: 64x64 tile, BK=16, 256 threads, 4x4 micro-tile (packed fp32),
// double-buffered. grid (4, 64, 3) = 768 blocks.
// ------------------------------------------------------------------
__global__ __launch_bounds__(256)
void proj_exp_kernel(const float* __restrict__ q, const float* __restrict__ kx,
                     const float* __restrict__ wq, const float* __restrict__ wk,
                     const float* __restrict__ V,
                     float* __restrict__ Eq, unsigned short* __restrict__ Ekb,
                     float* __restrict__ Vp)
{
    const int z = blockIdx.z;
    const int tid = threadIdx.x;
    if (z == 2) {
        const int L = blockIdx.y * 4 + blockIdx.x;        // 0..255
        #pragma unroll
        for (int j = 0; j < 4; ++j) {
            const int p   = L * 1024 + j * 256 + tid;
            const int bk4 = p >> 8;
            const int dv  = p & 255;
            const int b   = bk4 >> 6, k4 = bk4 & 63;
            const float* src = V + ((size_t)(b * Kn + 4 * k4)) * DVn + dv;
            float4 o;
            o.x = src[0 * DVn]; o.y = src[1 * DVn]; o.z = src[2 * DVn]; o.w = src[3 * DVn];
            *(float4*)(Vp + (size_t)p * 4) = o;
        }
        return;
    }
    const float* A = z ? kx : q;
    const float* W = z ? wk : wq;
    const int m0 = blockIdx.y * 64;
    const int n0 = blockIdx.x * 64;
    __shared__ __align__(16) float As[2][16][68];
    __shared__ __align__(16) float Bs[2][16][68];
    const int tx = tid & 15, ty = tid >> 4;
    const int lr = tid >> 2, lk4 = (tid & 3) * 4;
    const float* Arow = A + (size_t)(m0 + lr) * Hn + lk4;
    const float* Wrow = W + (size_t)(n0 + lr) * Hn + lk4;
    {
        float4 a = *(const float4*)(Arow);
        float4 w = *(const float4*)(Wrow);
        As[0][lk4+0][lr] = a.x; As[0][lk4+1][lr] = a.y; As[0][lk4+2][lr] = a.z; As[0][lk4+3][lr] = a.w;
        Bs[0][lk4+0][lr] = w.x; Bs[0][lk4+1][lr] = w.y; Bs[0][lk4+2][lr] = w.z; Bs[0][lk4+3][lr] = w.w;
    }
    __syncthreads();
    v2f acc2[4][2] = {};
    int cur = 0;
    for (int k0 = 0; k0 < Hn; k0 += 16) {
        float4 an, wn;
        const bool more = (k0 + 16 < Hn);
        if (more) {
            an = *(const float4*)(Arow + k0 + 16);
            wn = *(const float4*)(Wrow + k0 + 16);
        }
        #pragma unroll
        for (int kk = 0; kk < 16; ++kk) {
            float4 av = *(const float4*)&As[cur][kk][ty*4];
            float4 bv = *(const float4*)&Bs[cur][kk][tx*4];
            const v2f b01 = {bv.x, bv.y};
            const v2f b23 = {bv.z, bv.w};
            const float ar[4] = {av.x, av.y, av.z, av.w};
            #pragma unroll
            for (int i = 0; i < 4; ++i) {
                const v2f ai = {ar[i], ar[i]};
                acc2[i][0] = pk_fma(ai, b01, acc2[i][0]);
                acc2[i][1] = pk_fma(ai, b23, acc2[i][1]);
            }
        }
        if (more) {
            const int nxt = cur ^ 1;
            As[nxt][lk4+0][lr] = an.x; As[nxt][lk4+1][lr] = an.y; As[nxt][lk4+2][lr] = an.z; As[nxt][lk4+3][lr] = an.w;
            Bs[nxt][lk4+0][lr] = wn.x; Bs[nxt][lk4+1][lr] = wn.y; Bs[nxt][lk4+2][lr] = wn.z; Bs[nxt][lk4+3][lr] = wn.w;
            __syncthreads();
            cur = nxt;
        }
    }
    #pragma unroll
    for (int i = 0; i < 4; ++i) {
        float4 o;
        o.x = fast_exp2(C2 * acc2[i][0].x);
        o.y = fast_exp2(C2 * acc2[i][0].y);
        o.z = fast_exp2(C2 * acc2[i][1].x);
        o.w = fast_exp2(C2 * acc2[i][1].y);
        if (z == 0) {
            *(float4*)(Eq + (size_t)(m0 + ty*4 + i) * Hn + n0 + tx*4) = o;
        } else {
            const int m  = m0 + ty*4 + i;        // = b*256 + k
            const int bq = m >> 8, kk2 = m & 255;
            const int hg = (n0 + tx*4) >> 2;     // h/4
            ushort4 s;
            s.x = f2bf(o.x); s.y = f2bf(o.y); s.z = f2bf(o.z); s.w = f2bf(o.w);
            *(ushort4*)(Ekb + ((size_t)(bq * 64 + hg) * 256 + kk2) * 4) = s;
        }
    }
}

// ------------------------------------------------------------------
// K2 fused: scores + softmax + PV -> out
// grid (Q/4=64, B=16), block 256. Thread t owns k-column t for 4 q-rows.
//   score(q,k) = -2 * sum_h wv[h] * rcp(1 + Eq[q,h]*Ek[k,h])  (softmax shift-inv)
// rcp via packed magic+Newton (no trans op); all math v_pk_fma_f32,
// packed over h-pairs. ek: bf16 coalesced dwordx2, prefetched.
// PV packed over q-pairs, V in fp32 k-quad layout.
// ------------------------------------------------------------------
__global__ __launch_bounds__(256)
void fused_attn_kernel(const float* __restrict__ Eq, const unsigned short* __restrict__ Ekb,
                       const float* __restrict__ wv, const float* __restrict__ Vp,
                       float* __restrict__ out)
{
    const int b  = blockIdx.y;
    const int q0 = blockIdx.x * 4;
    __shared__ __align__(16) float sEq[4 * 256];
    __shared__ __align__(16) float swv[256];
    __shared__ __align__(16) float sPv[256 * 4];   // [k][q] quads
    __shared__ float sredM[4][4];
    __shared__ float sredS[4][4];
    const int tid = threadIdx.x;
    {
        const int qq = tid >> 6, h4 = (tid & 63) * 4;
        *(float4*)&sEq[qq*256 + h4] = *(const float4*)(Eq + (size_t)(b*Qn + q0 + qq) * Hn + h4);
        swv[tid] = wv[tid];
    }
    __syncthreads();

    const v2f one = {1.0f, 1.0f};
    v2f acc2[4] = {};
    // ek uint2 index: b*16384 + hg*256 + t  (hg = h/4); uint2 = h-quad bf16
    const uint2* ekp = (const uint2*)Ekb + (size_t)b * 16384 + tid;
    uint2 e[4];
    #pragma unroll
    for (int g = 0; g < 4; ++g) e[g] = ekp[g * 256];
    for (int it = 0; it < 16; ++it) {
        uint2 en[4];
        if (it < 15) {
            #pragma unroll
            for (int g = 0; g < 4; ++g) en[g] = ekp[(4*(it+1) + g) * 256];
        }
        const int h0 = it * 16;
        v2f eklo[4], ekhi[4];
        #pragma unroll
        for (int g = 0; g < 4; ++g) {
            eklo[g] = v2f{__uint_as_float(e[g].x << 16), __uint_as_float(e[g].x & 0xFFFF0000u)};
            ekhi[g] = v2f{__uint_as_float(e[g].y << 16), __uint_as_float(e[g].y & 0xFFFF0000u)};
        }
        #pragma unroll
        for (int qq = 0; qq < 4; ++qq) {
            v2f a = acc2[qq];
            #pragma unroll
            for (int g = 0; g < 4; ++g) {
                const float4 ea = *(const float4*)&sEq[qq*256 + h0 + 4*g];
                const float4 wa = *(const float4*)&swv[h0 + 4*g];
                const v2f eq01 = {ea.x, ea.y}, eq23 = {ea.z, ea.w};
                const v2f w01  = {wa.x, wa.y}, w23  = {wa.z, wa.w};
                v2f x = pk_fma(eq01, eklo[g], one);
                a = pk_fma(w01, pk_rcp(x), a);
                x = pk_fma(eq23, ekhi[g], one);
                a = pk_fma(w23, pk_rcp(x), a);
            }
            acc2[qq] = a;
        }
        #pragma unroll
        for (int g = 0; g < 4; ++g) e[g] = en[g];
    }

    // ---- softmax over k (scores = -2*(acc.x+acc.y)) ----
    const int w = tid >> 6, lane = tid & 63;
    float s4[4];
    #pragma unroll
    for (int qq = 0; qq < 4; ++qq) {
        s4[qq] = -2.0f * (acc2[qq].x + acc2[qq].y);
        float mx = s4[qq];
        #pragma unroll
        for (int off = 32; off; off >>= 1) mx = fmaxf(mx, __shfl_xor(mx, off, 64));
        if (lane == 0) sredM[qq][w] = mx;
    }
    __syncthreads();
    float pq[4];
    #pragma unroll
    for (int qq = 0; qq < 4; ++qq) {
        const float mx = fmaxf(fmaxf(sredM[qq][0], sredM[qq][1]),
                               fmaxf(sredM[qq][2], sredM[qq][3]));
        pq[qq] = fast_exp2(LOG2E * (s4[qq] - mx));
        float s = pq[qq];
        #pragma unroll
        for (int off = 32; off; off >>= 1) s += __shfl_xor(s, off, 64);
        if (lane == 0) sredS[qq][w] = s;
    }
    *(float4*)&sPv[tid * 4] = make_float4(pq[0], pq[1], pq[2], pq[3]);
    __syncthreads();
    float rinv[4];
    #pragma unroll
    for (int qq = 0; qq < 4; ++qq)
        rinv[qq] = fast_rcp(sredS[qq][0] + sredS[qq][1] + sredS[qq][2] + sredS[qq][3]);

    // ---- PV: thread owns dv = tid, 4 q-rows packed in q-pairs ----
    v2f accP0 = {0.f, 0.f}, accP1 = {0.f, 0.f};
    const float4* vp = (const float4*)Vp + (size_t)b * 64 * 256 + tid;  // [k4][dv] quads
    float4 vv = vp[0];
    for (int k4 = 0; k4 < 64; ++k4) {
        float4 vn;
        if (k4 < 63) vn = vp[(k4 + 1) * 256];
        const float vj[4] = {vv.x, vv.y, vv.z, vv.w};
        #pragma unroll
        for (int j = 0; j < 4; ++j) {
            const float4 p4 = *(const float4*)&sPv[(4*k4 + j) * 4];
            const v2f p01 = {p4.x, p4.y}, p23 = {p4.z, p4.w};
            const v2f vb = {vj[j], vj[j]};
            accP0 = pk_fma(p01, vb, accP0);
            accP1 = pk_fma(p23, vb, accP1);
        }
        vv = vn;
    }
    float* ob = out + (size_t)(b*Qn + q0) * DVn + tid;
    ob[0 * DVn] = accP0.x * rinv[0];
    ob[1 * DVn] = accP0.y * rinv[1];
    ob[2 * DVn] = accP1.x * rinv[2];
    ob[3 * DVn] = accP1.y * rinv[3];
}

extern "C" void kernel_launch(void* const* d_in, const int* in_sizes, int n_in,
                              void* d_out, int out_size, void* d_ws, size_t ws_size,
                              hipStream_t stream) {
    const float* queries = (const float*)d_in[0];  // [16,256,256]
    const float* keys    = (const float*)d_in[1];  // [16,256,256]
    const float* values  = (const float*)d_in[2];  // [16,256,256]
    const float* W_q     = (const float*)d_in[3];  // [256,256]
    const float* W_k     = (const float*)d_in[4];  // [256,256]
    const float* w_v     = (const float*)d_in[5];  // [256]
    float* out = (float*)d_out;

    // workspace: Eq fp32 4MB | Ek bf16 2MB | Vp fp32 4MB
    float*          Eq  = (float*)d_ws;
    unsigned short* Ekb = (unsigned short*)(Eq + (size_t)Bn * Qn * Hn);
    float*          Vp  = (float*)(Ekb + (size_t)Bn * Kn * Hn);

    proj_exp_kernel<<<dim3(4, 64, 3), 256, 0, stream>>>(queries, keys, W_q, W_k, values,
                                                        Eq, Ekb, Vp);
    fused_attn_kernel<<<dim3(64, 16), 256, 0, stream>>>(Eq, Ekb, w_v, Vp, out);
}

// Round 7
// 128.936 us; speedup vs baseline: 1.0731x; 1.0721x over previous
//
#include <hip/hip_runtime.h>
#include <hip/hip_fp16.h>

// B=16, Q=256, K=256, H=256, DV=256
#define Bn 16
#define Qn 256
#define Kn 256
#define Hn 256
#define DVn 256

constexpr float C2    = 2.8853900817779268f;   // 2/ln2 : e^{2x} = 2^(C2*x)
constexpr float LOG2E = 1.4426950408889634f;

typedef __attribute__((ext_vector_type(8))) short bf16x8;
typedef __attribute__((ext_vector_type(4))) float f32x4;

__device__ __forceinline__ float fast_exp2(float x) { return __builtin_amdgcn_exp2f(x); }
__device__ __forceinline__ float fast_rcp(float x)  { return __builtin_amdgcn_rcpf(x); }

__device__ __forceinline__ unsigned short f2bf(float x) {   // RNE fp32->bf16
    unsigned u = __float_as_uint(x);
    u += 0x7fffu + ((u >> 16) & 1u);
    return (unsigned short)(u >> 16);
}

// ------------------------------------------------------------------
// K0 prep: Xb = bf16(queries ++ keys)  [8192][256]  (2,097,152 elems)
//          Wb = bf16(W_q ++ W_k)      [2][256][256] (131,072 elems)
//          Vp = V re-tiled to k-quads fp32 [b][k/4][dv][4]
// grid 1024 x 256
// ------------------------------------------------------------------
__global__ __launch_bounds__(256)
void prep_kernel(const float* __restrict__ q, const float* __restrict__ kx,
                 const float* __restrict__ wq, const float* __restrict__ wk,
                 const float* __restrict__ V,
                 unsigned short* __restrict__ Xb, unsigned short* __restrict__ Wb,
                 float* __restrict__ Vp)
{
    const int g = blockIdx.x * 256 + threadIdx.x;   // 0..262143
    // X convert: 2M elements, 8 per thread
    {
        const float* xs = (g < 131072) ? (q + (size_t)g * 8)
                                       : (kx + (size_t)(g - 131072) * 8);
        float4 x0 = *(const float4*)xs;
        float4 x1 = *(const float4*)(xs + 4);
        ushort4 o0, o1;
        o0.x = f2bf(x0.x); o0.y = f2bf(x0.y); o0.z = f2bf(x0.z); o0.w = f2bf(x0.w);
        o1.x = f2bf(x1.x); o1.y = f2bf(x1.y); o1.z = f2bf(x1.z); o1.w = f2bf(x1.w);
        *(ushort4*)(Xb + (size_t)g * 8)     = o0;
        *(ushort4*)(Xb + (size_t)g * 8 + 4) = o1;
    }
    // W convert: 131072 elements, 4 per thread for g < 32768
    if (g < 32768) {
        const float* ws = (g < 16384) ? (wq + (size_t)g * 4)
                                      : (wk + (size_t)(g - 16384) * 4);
        float4 w0 = *(const float4*)ws;
        ushort4 o;
        o.x = f2bf(w0.x); o.y = f2bf(w0.y); o.z = f2bf(w0.z); o.w = f2bf(w0.w);
        *(ushort4*)(Wb + (size_t)g * 4) = o;
    }
    // V re-tile: quad p = g
    {
        const int p   = g;
        const int bk4 = p >> 8, dv = p & 255;
        const int b   = bk4 >> 6, k4 = bk4 & 63;
        const float* src = V + ((size_t)(b * Kn + 4 * k4)) * DVn + dv;
        float4 o;
        o.x = src[0 * DVn]; o.y = src[1 * DVn]; o.z = src[2 * DVn]; o.w = src[3 * DVn];
        *(float4*)(Vp + (size_t)p * 4) = o;
    }
}

// ------------------------------------------------------------------
// K1 proj (MFMA): rows 0..4095 = queries @ W_q^T -> Eq = exp(2*.) fp32 [4096][256]
//                 rows 4096..8191 = keys @ W_k^T -> Ek bf16 interleaved [b][h/4][k][4]
// block = 256 thr (4 waves); block covers 16 m-rows x 256 n; wave covers 64 n.
// A/B fragments straight from global (no LDS). grid 512.
// ------------------------------------------------------------------
__global__ __launch_bounds__(256)
void proj_mfma_kernel(const unsigned short* __restrict__ Xb,
                      const unsigned short* __restrict__ Wb,
                      float* __restrict__ Eq, unsigned short* __restrict__ Ekb)
{
    const int tid  = threadIdx.x;
    const int wvid = tid >> 6, lane = tid & 63;
    const int m0   = blockIdx.x * 16;          // 0..8191
    const int n0   = wvid * 64;
    const bool isQ = (m0 < 4096);
    const int r16  = lane & 15, q8 = (lane >> 4) * 8;

    const unsigned short* Xrow  = Xb + (size_t)(m0 + r16) * 256 + q8;
    const unsigned short* Wbase = Wb + (isQ ? 0 : 65536);

    bf16x8 afr[8];
    #pragma unroll
    for (int s = 0; s < 8; ++s) afr[s] = *(const bf16x8*)(Xrow + s * 32);

    f32x4 acc[4];
    #pragma unroll
    for (int nt = 0; nt < 4; ++nt) {
        const unsigned short* Wrow = Wbase + (size_t)(n0 + nt * 16 + r16) * 256 + q8;
        f32x4 c = {0.f, 0.f, 0.f, 0.f};
        #pragma unroll
        for (int s = 0; s < 8; ++s) {
            bf16x8 bfr = *(const bf16x8*)(Wrow + s * 32);
            c = __builtin_amdgcn_mfma_f32_16x16x32_bf16(afr[s], bfr, c, 0, 0, 0);
        }
        acc[nt] = c;
    }
    const int rbase = (lane >> 4) * 4;
    #pragma unroll
    for (int nt = 0; nt < 4; ++nt) {
        const int n = n0 + nt * 16 + r16;
        #pragma unroll
        for (int r = 0; r < 4; ++r) {
            const int m = m0 + rbase + r;
            const float val = fast_exp2(C2 * acc[nt][r]);
            if (isQ) {
                Eq[(size_t)m * 256 + n] = val;
            } else {
                const int kr = m - 4096, b = kr >> 8, kk = kr & 255;
                Ekb[(((size_t)(b * 64 + (n >> 2))) * 256 + kk) * 4 + (n & 3)] = f2bf(val);
            }
        }
    }
}

// ------------------------------------------------------------------
// K2 fused: scores + softmax + PV -> out
// grid (Q/4=64, B=16), block 256. Thread t owns k-column t for 4 q-rows.
//   score(q,k) = -2 * sum_h wv[h] * rcp(1 + Eq[q,h]*Ek[k,h])  (softmax shift-inv)
// eq/wv: block-uniform global reads -> scalar loads (no LDS!)
// ek: bf16 coalesced dwordx2, prefetched. V: fp32 k-quad b128, prefetched.
// ------------------------------------------------------------------
__global__ __launch_bounds__(256)
void fused_attn_kernel(const float* __restrict__ Eq, const unsigned short* __restrict__ Ekb,
                       const float* __restrict__ wv, const float* __restrict__ Vp,
                       float* __restrict__ out)
{
    const int b  = blockIdx.y;
    const int q0 = blockIdx.x * 4;
    __shared__ __align__(16) float sPv[256 * 4];   // [k][q] quads
    __shared__ float sredM[4][4];
    __shared__ float sredS[4][4];
    const int tid = threadIdx.x;

    const float* eq0 = Eq + (size_t)(b * Qn + q0) * Hn;   // block-uniform base

    float sc[4] = {0.f, 0.f, 0.f, 0.f};
    const uint2* ekp = (const uint2*)Ekb + (size_t)b * 16384 + tid;  // [b][h/4][k] quads
    uint2 e[4];
    #pragma unroll
    for (int g = 0; g < 4; ++g) e[g] = ekp[g * 256];
    for (int it = 0; it < 16; ++it) {
        uint2 en[4];
        if (it < 15) {
            #pragma unroll
            for (int g = 0; g < 4; ++g) en[g] = ekp[(4 * (it + 1) + g) * 256];
        }
        const int h0 = it * 16;
        float ek[16];
        #pragma unroll
        for (int g = 0; g < 4; ++g) {
            ek[4*g+0] = __uint_as_float(e[g].x << 16);
            ek[4*g+1] = __uint_as_float(e[g].x & 0xFFFF0000u);
            ek[4*g+2] = __uint_as_float(e[g].y << 16);
            ek[4*g+3] = __uint_as_float(e[g].y & 0xFFFF0000u);
        }
        #pragma unroll
        for (int g = 0; g < 4; ++g) {
            const float4 wa = *(const float4*)(wv + h0 + 4 * g);       // uniform -> s_load
            #pragma unroll
            for (int qq = 0; qq < 4; ++qq) {
                const float4 ea = *(const float4*)(eq0 + qq * 256 + h0 + 4 * g);  // uniform
                float a = sc[qq];
                a = fmaf(wa.x, fast_rcp(fmaf(ea.x, ek[4*g+0], 1.f)), a);
                a = fmaf(wa.y, fast_rcp(fmaf(ea.y, ek[4*g+1], 1.f)), a);
                a = fmaf(wa.z, fast_rcp(fmaf(ea.z, ek[4*g+2], 1.f)), a);
                a = fmaf(wa.w, fast_rcp(fmaf(ea.w, ek[4*g+3], 1.f)), a);
                sc[qq] = a;
            }
        }
        #pragma unroll
        for (int g = 0; g < 4; ++g) e[g] = en[g];
    }

    // ---- softmax over k (scores = -2*sc) ----
    const int w = tid >> 6, lane = tid & 63;
    #pragma unroll
    for (int qq = 0; qq < 4; ++qq) {
        sc[qq] = -2.0f * sc[qq];
        float mx = sc[qq];
        #pragma unroll
        for (int off = 32; off; off >>= 1) mx = fmaxf(mx, __shfl_xor(mx, off, 64));
        if (lane == 0) sredM[qq][w] = mx;
    }
    __syncthreads();
    float pq[4];
    #pragma unroll
    for (int qq = 0; qq < 4; ++qq) {
        const float mx = fmaxf(fmaxf(sredM[qq][0], sredM[qq][1]),
                               fmaxf(sredM[qq][2], sredM[qq][3]));
        pq[qq] = fast_exp2(LOG2E * (sc[qq] - mx));
        float s = pq[qq];
        #pragma unroll
        for (int off = 32; off; off >>= 1) s += __shfl_xor(s, off, 64);
        if (lane == 0) sredS[qq][w] = s;
    }
    *(float4*)&sPv[tid * 4] = make_float4(pq[0], pq[1], pq[2], pq[3]);
    __syncthreads();
    float rinv[4];
    #pragma unroll
    for (int qq = 0; qq < 4; ++qq)
        rinv[qq] = fast_rcp(sredS[qq][0] + sredS[qq][1] + sredS[qq][2] + sredS[qq][3]);

    // ---- PV: thread owns dv = tid, 4 q-rows; V in fp32 k-quad layout ----
    float acc[4] = {0.f, 0.f, 0.f, 0.f};
    const float4* vp = (const float4*)Vp + (size_t)b * 64 * 256 + tid;
    float4 vv = vp[0];
    for (int k4 = 0; k4 < 64; ++k4) {
        float4 vn;
        if (k4 < 63) vn = vp[(k4 + 1) * 256];
        const float vj[4] = {vv.x, vv.y, vv.z, vv.w};
        #pragma unroll
        for (int j = 0; j < 4; ++j) {
            const float4 p4 = *(const float4*)&sPv[(4 * k4 + j) * 4];
            acc[0] = fmaf(p4.x, vj[j], acc[0]);
            acc[1] = fmaf(p4.y, vj[j], acc[1]);
            acc[2] = fmaf(p4.z, vj[j], acc[2]);
            acc[3] = fmaf(p4.w, vj[j], acc[3]);
        }
        vv = vn;
    }
    float* ob = out + (size_t)(b * Qn + q0) * DVn + tid;
    ob[0 * DVn] = acc[0] * rinv[0];
    ob[1 * DVn] = acc[1] * rinv[1];
    ob[2 * DVn] = acc[2] * rinv[2];
    ob[3 * DVn] = acc[3] * rinv[3];
}

extern "C" void kernel_launch(void* const* d_in, const int* in_sizes, int n_in,
                              void* d_out, int out_size, void* d_ws, size_t ws_size,
                              hipStream_t stream) {
    const float* queries = (const float*)d_in[0];  // [16,256,256]
    const float* keys    = (const float*)d_in[1];  // [16,256,256]
    const float* values  = (const float*)d_in[2];  // [16,256,256]
    const float* W_q     = (const float*)d_in[3];  // [256,256]
    const float* W_k     = (const float*)d_in[4];  // [256,256]
    const float* w_v     = (const float*)d_in[5];  // [256]
    float* out = (float*)d_out;

    // workspace: Eq fp32 4MB | Ekb bf16 2MB | Vp fp32 4MB | Xb bf16 4MB | Wb bf16 256KB
    float*          Eq  = (float*)d_ws;
    unsigned short* Ekb = (unsigned short*)(Eq + (size_t)Bn * Qn * Hn);
    float*          Vp  = (float*)(Ekb + (size_t)Bn * Kn * Hn);
    unsigned short* Xb  = (unsigned short*)(Vp + (size_t)Bn * Kn * DVn);
    unsigned short* Wb  = Xb + (size_t)2 * Bn * Qn * Hn;   // Xb holds 2*Bn*Qn*Hn bf16 elems

    prep_kernel<<<dim3(1024), 256, 0, stream>>>(queries, keys, W_q, W_k, values,
                                                Xb, Wb, Vp);
    proj_mfma_kernel<<<dim3(512), 256, 0, stream>>>(Xb, Wb, Eq, Ekb);
    fused_attn_kernel<<<dim3(64, 16), 256, 0, stream>>>(Eq, Ekb, w_v, Vp, out);
}